// Round 20
// baseline (145.589 us; speedup 1.0000x reference)
//
#include <hip/hip_runtime.h>
#include <stdint.h>

#define N_ATOMS 100000
#define N_EDGES 625000
#define N_MOL   1000
#define EMB_ATOM 256
#define EMB_EDGE 128

typedef float f32x4 __attribute__((ext_vector_type(4)));
typedef __attribute__((address_space(1))) const uint32_t gu32;
typedef __attribute__((address_space(3))) uint32_t su32;

__device__ __forceinline__ float dot4(f32x4 a, f32x4 b) {
    return a.x * b.x + a.y * b.y + a.z * b.z + a.w * b.w;
}

// ---- workspace layout (floats) ----
#define REP      8
#define YREP_STR 1024
#define FREP_OFF 8192
#define FREP_STR 300000
#define WS_FLOATS (FREP_OFF + REP * FREP_STR)    // 2408192 (= 602048 f32x4)

__global__ __launch_bounds__(256) void zero_kernel(f32x4* __restrict__ p, int n4)
{
    const int i = blockIdx.x * blockDim.x + threadIdx.x;
    if (i < n4) p[i] = (f32x4)(0.f, 0.f, 0.f, 0.f);
}

__global__ __launch_bounds__(256) void merge_kernel(
    const float* __restrict__ ws, float* __restrict__ out)
{
    const int i = blockIdx.x * blockDim.x + threadIdx.x;
    if (i >= 250 + 75000) return;
    const f32x4* w4 = reinterpret_cast<const f32x4*>(ws);
    f32x4*       o4 = reinterpret_cast<f32x4*>(out);
    if (i < 250) {
        f32x4 s = (f32x4)(0.f, 0.f, 0.f, 0.f);
        #pragma unroll
        for (int k = 0; k < REP; ++k) s += w4[i + k * (YREP_STR/4)];
        o4[i] = s;
    } else {
        const int j = i - 250;
        const f32x4* f4 = w4 + FREP_OFF/4;
        f32x4 s = (f32x4)(0.f, 0.f, 0.f, 0.f);
        #pragma unroll
        for (int k = 0; k < REP; ++k) s += f4[j + k * (FREP_STR/4)];
        o4[i] = s;
    }
}

// Unified persistent kernel. Work units: [0, FTILES) = forces tiles
// (16 edges each, staged via global_load_lds DMA); [FTILES, FTILES+ETILES)
// = energy tiles (8 atoms each, VGPR+NT path). One global work list ->
// auto-balanced across all 5120 wave-slots regardless of per-path rates.
//
// Forces tile: 8x global_load_lds_dwordx4 (1KB each: edge pair 2j,2j+1)
// into the wave's PRIVATE 8KB LDS slice -> s_waitcnt vmcnt(0) (wave-local,
// no barrier) -> per pair: contiguous ds_read_b128 (lane i reads byte i*16,
// conflict-free), dot with W[lane&31], 5-stage butterfly within 32-lane
// halves, lanes p<3 scatter to the force replica.
#define FTILES  ((N_EDGES + 15) / 16)            // 39063
#define ETILES  (N_ATOMS / 8)                    // 12500 exact
#define TOTAL_UNITS (FTILES + ETILES)            // 51563
#define NBLOCKS 1280                             // 5 blocks/CU (32KB LDS each)
#define NSLOTS  (NBLOCKS * 4)                    // 5120 wave-slots

__global__ __launch_bounds__(256) void fused_kernel(
    const float* __restrict__ h_energy,
    const float* __restrict__ h_forces,
    const float* __restrict__ V_st,
    const int*   __restrict__ idx_t,
    const int*   __restrict__ batch_idx,
    const float* __restrict__ W_energy,
    const float* __restrict__ W_forces,
    const float* __restrict__ b_forces,
    float*       __restrict__ ws)
{
    __shared__ __align__(16) char smem[4][8192];

    const int lane  = threadIdx.x & 63;
    const int widx  = threadIdx.x >> 6;
    const int wslot = blockIdx.x * 4 + widx;
    char* lbase = smem[widx];

    // forces fragments: lane p owns 4 floats of the 128-float row
    const int p    = lane & 31;
    const int half = lane >> 5;
    const f32x4* wf = reinterpret_cast<const f32x4*>(W_forces);
    const f32x4  wb = wf[p];
    const float bias = b_forces[0];

    // energy fragments (16 lanes per atom row)
    const int esub  = lane & 15;
    const int eslot = lane >> 4;
    const f32x4* we = reinterpret_cast<const f32x4*>(W_energy);
    const f32x4 eb0 = we[esub +  0];
    const f32x4 eb1 = we[esub + 16];
    const f32x4 eb2 = we[esub + 32];
    const f32x4 eb3 = we[esub + 48];

    float* frep = ws + FREP_OFF + (wslot & (REP-1)) * FREP_STR;
    float* yrep = ws + (wslot & (REP-1)) * YREP_STR;

    const char*  fbase = reinterpret_cast<const char*>(h_forces);
    const f32x4* ebase4 = reinterpret_cast<const f32x4*>(h_energy);

    for (int u = wslot; u < TOTAL_UNITS; u += NSLOTS) {
        if (u < FTILES) {
            // ---------------- forces tile (DMA path) ----------------
            const int e0 = u * 16;
            const char* gsrc = fbase + (size_t)e0 * 512 + (size_t)lane * 16;

            #pragma unroll
            for (int j = 0; j < 8; ++j) {
                if (e0 + 2*j < N_EDGES) {   // wave-uniform guard (tail tile)
                    __builtin_amdgcn_global_load_lds(
                        (gu32*)(const void*)(gsrc + j * 1024),
                        (su32*)(void*)(lbase + j * 1024),
                        16, 0, 0);
                }
            }
            asm volatile("s_waitcnt vmcnt(0)" ::: "memory");
            __builtin_amdgcn_sched_barrier(0);

            #pragma unroll
            for (int j = 0; j < 8; ++j) {
                const int e = e0 + 2*j + half;
                if (e0 + 2*j < N_EDGES) {
                    f32x4 r = *reinterpret_cast<const f32x4*>(lbase + j * 1024 + lane * 16);
                    float s = dot4(r, wb);
                    s += __shfl_xor(s, 1, 64);
                    s += __shfl_xor(s, 2, 64);
                    s += __shfl_xor(s, 4, 64);
                    s += __shfl_xor(s, 8, 64);
                    s += __shfl_xor(s, 16, 64);
                    if (p < 3 && e < N_EDGES) {
                        const int   t = idx_t[e];
                        const float v = V_st[(size_t)e * 3 + p];
                        atomicAdd(&frep[(size_t)t * 3 + p], (s + bias) * v);
                    }
                }
            }
        } else {
            // ---------------- energy tile (VGPR+NT path) ----------------
            const int tile = u - FTILES;
            #pragma unroll
            for (int g = 0; g < 2; ++g) {
                const int a = tile * 8 + g * 4 + eslot;   // < 100000 exact
                const f32x4* row = ebase4 + (size_t)a * 64;
                f32x4 a0 = __builtin_nontemporal_load(row + esub + 0);
                f32x4 a1 = __builtin_nontemporal_load(row + esub + 16);
                f32x4 a2 = __builtin_nontemporal_load(row + esub + 32);
                f32x4 a3 = __builtin_nontemporal_load(row + esub + 48);
                float s = dot4(a0, eb0) + dot4(a1, eb1) + dot4(a2, eb2) + dot4(a3, eb3);

                s += __shfl_xor(s, 1, 64);
                s += __shfl_xor(s, 2, 64);
                s += __shfl_xor(s, 4, 64);
                s += __shfl_xor(s, 8, 64);

                if (esub == 0) atomicAdd(&yrep[batch_idx[a]], s);
            }
        }
    }
}

extern "C" void kernel_launch(void* const* d_in, const int* in_sizes, int n_in,
                              void* d_out, int out_size, void* d_ws, size_t ws_size,
                              hipStream_t stream) {
    const float* h_energy  = (const float*)d_in[0];
    const float* h_forces  = (const float*)d_in[1];
    const float* V_st      = (const float*)d_in[2];
    const int*   idx_t     = (const int*)d_in[3];
    const int*   batch_idx = (const int*)d_in[4];
    const float* W_energy  = (const float*)d_in[5];
    const float* W_forces  = (const float*)d_in[6];
    const float* b_forces  = (const float*)d_in[7];

    float* ws  = (float*)d_ws;
    float* out = (float*)d_out;

    // Zero replica accumulators (2408192 floats = 602048 f32x4 = 9.6 MB).
    const int zn4 = WS_FLOATS / 4;
    zero_kernel<<<(zn4 + 255) / 256, 256, 0, stream>>>((f32x4*)d_ws, zn4);

    // Unified persistent kernel: 1280 blocks, all resident (5/CU via LDS).
    fused_kernel<<<NBLOCKS, 256, 0, stream>>>(
        h_energy, h_forces, V_st, idx_t, batch_idx,
        W_energy, W_forces, b_forces, ws);

    // Merge replicas -> d_out (75250 f32x4 elements).
    merge_kernel<<<(75250 + 255) / 256, 256, 0, stream>>>(ws, out);
}